// Round 12
// baseline (203.043 us; speedup 1.0000x reference)
//
#include <hip/hip_runtime.h>

typedef __attribute__((ext_vector_type(8))) short bf16x8;
typedef __attribute__((ext_vector_type(4))) float f32x4;

#define HIDDEN 2880
#define QKV_DIM 5120
#define NH 64
#define NKV 8
#define HD 64
#define ATT_DIM 4096
#define WINDOW 128
#define SM_SCALE 0.125f

__device__ __forceinline__ ushort f2bf(float f) {
  union { float f; unsigned u; } a; a.f = f;
  unsigned r = a.u + 0x7fffu + ((a.u >> 16) & 1u);
  return (ushort)(r >> 16);
}
__device__ __forceinline__ float bf2f(ushort u) {
  union { unsigned u; float f; } a; a.u = ((unsigned)u) << 16;
  return a.f;
}

__device__ __forceinline__ void gload_lds16(const void* g, void* l) {
  __builtin_amdgcn_global_load_lds((const __attribute__((address_space(1))) void*)g,
                                   (__attribute__((address_space(3))) void*)l, 16, 0, 0);
}

// ------- fused: RMSNorm (blocks [0,n)) + qkv_w f32->bf16 cvt (blocks [n, n+1024)) -------
__global__ __launch_bounds__(256)
void norm_cvt(const float* __restrict__ x, const float* __restrict__ scale,
              ushort* __restrict__ t, int n,
              const float* __restrict__ w, ushort* __restrict__ wout, int n4w) {
  int tid = threadIdx.x;
  if ((int)blockIdx.x >= n) {
    int i = ((int)blockIdx.x - n) * 256 + tid;
    int stride = (gridDim.x - n) * 256;
    for (; i < n4w; i += stride) {
      float4 v = ((const float4*)w)[i];
      ushort4 o = { f2bf(v.x), f2bf(v.y), f2bf(v.z), f2bf(v.w) };
      ((ushort4*)wout)[i] = o;
    }
    return;
  }
  int row = blockIdx.x;
  const float4* xr = (const float4*)(x + (size_t)row * HIDDEN);
  float4 a0 = xr[tid];
  float4 a1 = xr[tid + 256];
  bool has2 = tid < 208;
  float4 a2 = has2 ? xr[tid + 512] : float4{0.f, 0.f, 0.f, 0.f};
  float ss = a0.x*a0.x + a0.y*a0.y + a0.z*a0.z + a0.w*a0.w
           + a1.x*a1.x + a1.y*a1.y + a1.z*a1.z + a1.w*a1.w
           + a2.x*a2.x + a2.y*a2.y + a2.z*a2.z + a2.w*a2.w;
  for (int m = 1; m < 64; m <<= 1) ss += __shfl_xor(ss, m, 64);
  __shared__ float red[4];
  if ((tid & 63) == 0) red[tid >> 6] = ss;
  __syncthreads();
  ss = red[0] + red[1] + red[2] + red[3];
  float r = rsqrtf(ss / (float)HIDDEN + 1e-5f);
  ushort4* tr = (ushort4*)(t + (size_t)row * HIDDEN);
  const float4* sc4 = (const float4*)scale;
  {
    float4 s = sc4[tid];
    ushort4 o = { f2bf(a0.x*r*s.x), f2bf(a0.y*r*s.y), f2bf(a0.z*r*s.z), f2bf(a0.w*r*s.w) };
    tr[tid] = o;
  }
  {
    float4 s = sc4[tid + 256];
    ushort4 o = { f2bf(a1.x*r*s.x), f2bf(a1.y*r*s.y), f2bf(a1.z*r*s.z), f2bf(a1.w*r*s.w) };
    tr[tid + 256] = o;
  }
  if (has2) {
    float4 s = sc4[tid + 512];
    ushort4 o = { f2bf(a2.x*r*s.x), f2bf(a2.y*r*s.y), f2bf(a2.z*r*s.z), f2bf(a2.w*r*s.w) };
    tr[tid + 512] = o;
  }
}

// ---- 128x128 8-phase-style pipelined bf16 GEMM, 4 waves, 64KB LDS -> 2 blocks/CU ----
// EXACT R7 phase/race structure at half tile: A regions (32-row) read P1(mh0:r0,r2)/
// P3(mh1:r1,r3), staged P2/P4; all B LDS reads done by P2-end, staged P3; counted
// vmcnt(8) per tile (one tile's 8 stage-instrs/wave in flight), never 0 in steady state.
// 2 co-resident blocks/CU let one block's MFMA cover the other's barrier waits (m114).
template <int MASK_N, int FUSE_BIAS>
__global__ __launch_bounds__(256)
void gemm_128(const ushort* __restrict__ A, const ushort* __restrict__ B,
              const float* __restrict__ bias, ushort* __restrict__ P,
              int M, int N, int K, int NSK) {
  __shared__ __align__(16) ushort Al[2][128 * 64];
  __shared__ __align__(16) ushort Bl[2][128 * 64];
  const int tid = threadIdx.x;
  const int wave = tid >> 6, lane = tid & 63;
  const int l15 = lane & 15, hi = lane >> 4;

  int nwg = gridDim.x, orig = blockIdx.x;
  int q8 = nwg >> 3, r8 = nwg & 7, xcd = orig & 7, seq = orig >> 3;
  int swz = (xcd < r8 ? xcd * (q8 + 1) : r8 * (q8 + 1) + (xcd - r8) * q8) + seq;
  int nm = M >> 7;
  int bm = swz % nm, bn = swz / nm;
  const int row0 = bm * 128, col0 = bn * 128;
  const int sk = blockIdx.y;
  const int NTtot = K >> 6;
  const int tt0 = sk * NTtot / NSK, tt1 = (sk + 1) * NTtot / NSK;
  ushort* Pp = P + (size_t)sk * M * N;

  const int wrow = (wave >> 1) * 64;
  const int wcol = (wave & 1) * 64;
  const int srow = lane >> 3;
  const int schunk = (lane & 7) ^ srow;

  f32x4 acc[4][4] = {};

  auto stageA = [&](int t, int r) {
    int rowb = r * 32 + wave * 8;
    gload_lds16(A + (size_t)(row0 + rowb + srow) * K + (t << 6) + schunk * 8,
                &Al[t & 1][rowb * 64]);
  };
  auto stageB = [&](int t, int r) {
    int rowb = r * 32 + wave * 8;
    int brow = col0 + rowb + srow;
    if (MASK_N) { if (brow > N - 1) brow = N - 1; }
    gload_lds16(B + (size_t)brow * K + (t << 6) + schunk * 8,
                &Bl[t & 1][rowb * 64]);
  };
  auto stageAll = [&](int t) {
#pragma unroll
    for (int r = 0; r < 4; ++r) { stageA(t, r); stageB(t, r); }
  };
  auto LDA = [&](bf16x8 (&dst)[2][2], int mh, const char* base) {
#pragma unroll
    for (int mt = 0; mt < 2; ++mt)
#pragma unroll
      for (int ks = 0; ks < 2; ++ks) {
        int rr = wrow + (mh * 2 + mt) * 16 + l15;
        int off = (rr * 128 + ks * 64 + hi * 16) ^ ((rr & 7) << 4);
        dst[mt][ks] = *(const bf16x8*)(base + off);
      }
  };
  auto LDB = [&](bf16x8 (&dst)[2][2], int nh, const char* base) {
#pragma unroll
    for (int nt = 0; nt < 2; ++nt)
#pragma unroll
      for (int ks = 0; ks < 2; ++ks) {
        int rr = wcol + (nh * 2 + nt) * 16 + l15;
        int off = (rr * 128 + ks * 64 + hi * 16) ^ ((rr & 7) << 4);
        dst[nt][ks] = *(const bf16x8*)(base + off);
      }
  };
  auto MMA = [&](bf16x8 (&a)[2][2], bf16x8 (&b)[2][2], int mh, int nh) {
    __builtin_amdgcn_s_setprio(1);
#pragma unroll
    for (int ks = 0; ks < 2; ++ks)
#pragma unroll
      for (int nt = 0; nt < 2; ++nt)
#pragma unroll
        for (int mt = 0; mt < 2; ++mt)
          acc[mh * 2 + mt][nh * 2 + nt] = __builtin_amdgcn_mfma_f32_16x16x32_bf16(
              a[mt][ks], b[nt][ks], acc[mh * 2 + mt][nh * 2 + nt], 0, 0, 0);
    __builtin_amdgcn_s_setprio(0);
  };

  stageAll(tt0);
  bool two = (tt1 - tt0 > 1);
  if (two) {
    stageAll(tt0 + 1);
    asm volatile("s_waitcnt vmcnt(8)" ::: "memory");
  } else {
    asm volatile("s_waitcnt vmcnt(0)" ::: "memory");
  }
  __builtin_amdgcn_s_barrier();

  for (int t = tt0; t < tt1; ++t) {
    const char* Ab = (const char*)&Al[t & 1][0];
    const char* Bb = (const char*)&Bl[t & 1][0];
    bool pre = (t + 2 < tt1);
    bf16x8 afr[2][2], bf0[2][2], bf1[2][2];
    // P1: A mh0 (rows r0,r2 regions) + B nh0
    LDA(afr, 0, Ab);
    LDB(bf0, 0, Bb);
    __builtin_amdgcn_s_barrier();
    MMA(afr, bf0, 0, 0);
    __builtin_amdgcn_s_barrier();
    // P2: B nh1; stage A(t+2) regions read in P1 (r0, r2)
    LDB(bf1, 1, Bb);
    if (pre) { stageA(t + 2, 0); stageA(t + 2, 2); }
    __builtin_amdgcn_s_barrier();
    MMA(afr, bf1, 0, 1);
    __builtin_amdgcn_s_barrier();
    // P3: A mh1; all B LDS reads done by P2-end -> stage all B(t+2)
    LDA(afr, 1, Ab);
    if (pre) { stageB(t + 2, 0); stageB(t + 2, 1); stageB(t + 2, 2); stageB(t + 2, 3); }
    __builtin_amdgcn_s_barrier();
    MMA(afr, bf1, 1, 1);
    __builtin_amdgcn_s_barrier();
    // P4: stage A(t+2) regions read in P3 (r1, r3)
    if (pre) { stageA(t + 2, 1); stageA(t + 2, 3); }
    __builtin_amdgcn_s_barrier();
    MMA(afr, bf0, 1, 0);
    if (pre) asm volatile("s_waitcnt vmcnt(8)" ::: "memory");
    else     asm volatile("s_waitcnt vmcnt(0)" ::: "memory");
    __builtin_amdgcn_s_barrier();
  }

  // epilogue: C/D layout col=lane&15, row=(lane>>4)*4+r (m89-verified); bf16 out
#pragma unroll
  for (int mt = 0; mt < 4; ++mt) {
#pragma unroll
    for (int nt = 0; nt < 4; ++nt) {
#pragma unroll
      for (int rr = 0; rr < 4; ++rr) {
        int row = row0 + wrow + mt * 16 + (hi << 2) + rr;
        int col = col0 + wcol + nt * 16 + l15;
        if (!MASK_N || col < N) {
          float v = acc[mt][nt][rr];
          if (FUSE_BIAS) v += bias[col];
          Pp[(size_t)row * N + col] = f2bf(v);
        }
      }
    }
  }
}

// ---------------- out reduce: out = x + out_b + sum_sk bf16 partials ----------------
__global__ __launch_bounds__(256)
void reduce_out(const float* __restrict__ x, const float* __restrict__ b,
                const ushort* __restrict__ p, int nsk, size_t stride,
                float* __restrict__ out, int n4, int N) {
  int i = blockIdx.x * blockDim.x + threadIdx.x;
  if (i >= n4) return;
  float4 v = ((const float4*)x)[i];
  int col = (i * 4) % N;
  float4 bb = *(const float4*)(b + col);
  v.x += bb.x; v.y += bb.y; v.z += bb.z; v.w += bb.w;
  for (int s = 0; s < nsk; ++s) {
    ushort4 pv = *(const ushort4*)(p + s * stride + (size_t)i * 4);
    v.x += bf2f(pv.x); v.y += bf2f(pv.y); v.z += bf2f(pv.z); v.w += bf2f(pv.w);
  }
  ((float4*)out)[i] = v;
}

// ---------- RoPE + split (reads bias-fused bf16 qkv; no partial reduce) ----------
__global__ __launch_bounds__(256)
void rope_split(const ushort* __restrict__ qkv,
                ushort* __restrict__ qb, ushort* __restrict__ kb, ushort* __restrict__ vb) {
  int tok = blockIdx.x;
  int tid = threadIdx.x;
  __shared__ float cs[32], sn[32];
  if (tid < 32) {
    float d = (float)tid;
    float freq = powf(150000.0f, d / 32.0f);
    float conc = 0.1f * logf(32.0f) + 1.0f;
    float lg = logf(150000.0f);
    float low = 32.0f * logf(4096.0f / (32.0f * 6.2831853f)) / lg;
    float high = 32.0f * logf(4096.0f / 6.2831853f) / lg;
    float ramp = (d - low) / (high - low);
    float cl = fminf(fmaxf(ramp, 0.0f), 1.0f);
    float mask = 1.0f - cl;
    float inv_freq = (1.0f - mask) / (32.0f * freq) + mask / freq;
    float fr = (float)tok * inv_freq;
    cs[tid] = cosf(fr) * conc;
    sn[tid] = sinf(fr) * conc;
  }
  __syncthreads();
  const ushort* row = qkv + (size_t)tok * QKV_DIM;
#pragma unroll
  for (int it = 0; it < 8; ++it) {
    int pp = tid + it * 256;
    int hd = pp >> 5, d = pp & 31;
    float x1 = bf2f(row[hd * 64 + d]), x2 = bf2f(row[hd * 64 + d + 32]);
    float c = cs[d], s = sn[d];
    size_t o = ((size_t)tok * NH + hd) * HD + d;
    qb[o] = f2bf(x1 * c - x2 * s);
    qb[o + 32] = f2bf(x2 * c + x1 * s);
  }
  {
    int pp = tid;
    int hd = pp >> 5, d = pp & 31;
    float x1 = bf2f(row[4096 + hd * 64 + d]), x2 = bf2f(row[4096 + hd * 64 + d + 32]);
    float c = cs[d], s = sn[d];
    size_t o = ((size_t)tok * NKV + hd) * HD + d;
    kb[o] = f2bf(x1 * c - x2 * s);
    kb[o + 32] = f2bf(x2 * c + x1 * s);
  }
#pragma unroll
  for (int it = 0; it < 2; ++it) {
    int pp = tid + it * 256;
    vb[(size_t)tok * (NKV * HD) + pp] = row[4608 + pp];  // already biased bf16
  }
}

// ---- attention (sliding window 128 + sink, 16 q/wave) + hidden out_w f32->bf16 cvt ----
__global__ __launch_bounds__(512)
void attn_cvt(const ushort* __restrict__ qb, const ushort* __restrict__ kb,
              const ushort* __restrict__ vb, const float* __restrict__ sinks,
              ushort* __restrict__ attn, int n, int nattn,
              const float* __restrict__ w, ushort* __restrict__ wout, int n4w) {
  __shared__ __align__(16) ushort Kl[160 * 64];
  __shared__ __align__(16) ushort Vt[64 * 168];
  __shared__ __align__(16) ushort Pl[8][16 * 40];
  int tid = threadIdx.x;
  if ((int)blockIdx.x >= nattn) {
    int i = ((int)blockIdx.x - nattn) * 512 + tid;
    int stride = (gridDim.x - nattn) * 512;
    for (; i < n4w; i += stride) {
      float4 v = ((const float4*)w)[i];
      ushort4 o = { f2bf(v.x), f2bf(v.y), f2bf(v.z), f2bf(v.w) };
      ((ushort4*)wout)[i] = o;
    }
    return;
  }
  int wave = tid >> 6, lane = tid & 63;
  int l15 = lane & 15, hi = lane >> 4;
  int qstart = ((int)blockIdx.x >> 3) * 16;
  int kv = (int)blockIdx.x & 7;
  int head = kv * 8 + wave;
  int key0 = qstart - 128;

  for (int i = 0; i < 3; ++i) {
    int rowb = i * 64 + wave * 8;
    if (rowb < 160) {
      int r = rowb + (lane >> 3);
      int gj = key0 + r; if (gj < 0) gj = 0;
      int chunk = (lane & 7) ^ (lane >> 3);
      gload_lds16(kb + ((size_t)gj * NKV + kv) * HD + chunk * 8, Kl + rowb * 64);
    }
  }
  for (int e = tid; e < 160 * 16; e += 512) {
    int j = e >> 4, d4 = (e & 15) << 2;
    int gj = key0 + j; if (gj < 0) gj = 0;
    ushort4 v = *(const ushort4*)(vb + ((size_t)gj * NKV + kv) * HD + d4);
    Vt[(d4 + 0) * 168 + j] = v.x;
    Vt[(d4 + 1) * 168 + j] = v.y;
    Vt[(d4 + 2) * 168 + j] = v.z;
    Vt[(d4 + 3) * 168 + j] = v.w;
  }
  bf16x8 qf[2];
#pragma unroll
  for (int ks = 0; ks < 2; ++ks) {
    int r = qstart + l15;
    int kk = ks * 32 + hi * 8;
    qf[ks] = *(const bf16x8*)(qb + ((size_t)r * NH + head) * HD + kk);
  }
  __syncthreads();

  f32x4 s[10] = {};
#pragma unroll
  for (int nt = 0; nt < 10; ++nt) {
#pragma unroll
    for (int ks = 0; ks < 2; ++ks) {
      int r = nt * 16 + l15;
      int off = (r * 128 + (ks * 32 + hi * 8) * 2) ^ ((r & 7) << 4);
      bf16x8 kf = *(const bf16x8*)((const char*)Kl + off);
      s[nt] = __builtin_amdgcn_mfma_f32_16x16x32_bf16(qf[ks], kf, s[nt], 0, 0, 0);
    }
  }

  float lrow[4];
  float snk = sinks[head];
#pragma unroll
  for (int r = 0; r < 4; ++r) {
    int i = qstart + hi * 4 + r;
    float mx = -1e30f;
#pragma unroll
    for (int nt = 0; nt < 10; ++nt) {
      int j = key0 + nt * 16 + l15;
      bool ok = (j >= 0) && (j <= i) && (j > i - WINDOW);
      float val = ok ? s[nt][r] * SM_SCALE : -1e30f;
      s[nt][r] = val;
      mx = fmaxf(mx, val);
    }
    mx = fmaxf(mx, __shfl_xor(mx, 1, 64));
    mx = fmaxf(mx, __shfl_xor(mx, 2, 64));
    mx = fmaxf(mx, __shfl_xor(mx, 4, 64));
    mx = fmaxf(mx, __shfl_xor(mx, 8, 64));
    mx = fmaxf(mx, snk);
    float sum = 0.f;
#pragma unroll
    for (int nt = 0; nt < 10; ++nt) {
      float pv = __expf(s[nt][r] - mx);
      s[nt][r] = pv;
      sum += pv;
    }
    sum += __shfl_xor(sum, 1, 64);
    sum += __shfl_xor(sum, 2, 64);
    sum += __shfl_xor(sum, 4, 64);
    sum += __shfl_xor(sum, 8, 64);
    sum += __expf(snk - mx);
    lrow[r] = sum;
  }

  f32x4 o[4] = {};
#pragma unroll
  for (int kc = 0; kc < 5; ++kc) {
#pragma unroll
    for (int t2 = 0; t2 < 2; ++t2) {
      int nt = kc * 2 + t2;
#pragma unroll
      for (int r = 0; r < 4; ++r)
        Pl[wave][(hi * 4 + r) * 40 + t2 * 16 + l15] = f2bf(s[nt][r]);
    }
    bf16x8 pa = *(const bf16x8*)(&Pl[wave][l15 * 40 + hi * 8]);
#pragma unroll
    for (int nt = 0; nt < 4; ++nt) {
      int d = nt * 16 + l15;
      int kk = kc * 32 + hi * 8;
      bf16x8 vf = *(const bf16x8*)(&Vt[d * 168 + kk]);
      o[nt] = __builtin_amdgcn_mfma_f32_16x16x32_bf16(pa, vf, o[nt], 0, 0, 0);
    }
  }

#pragma unroll
  for (int nt = 0; nt < 4; ++nt)
#pragma unroll
    for (int r = 0; r < 4; ++r) {
      int row = qstart + hi * 4 + r;
      int d = nt * 16 + l15;
      float val = o[nt][r] / lrow[r];
      attn[((size_t)row * NH + head) * HD + d] = f2bf(val);
    }
}

extern "C" void kernel_launch(void* const* d_in, const int* in_sizes, int n_in,
                              void* d_out, int out_size, void* d_ws, size_t ws_size,
                              hipStream_t stream) {
  const float* x      = (const float*)d_in[0];
  const float* nscale = (const float*)d_in[1];
  const float* qkv_w  = (const float*)d_in[2];
  const float* qkv_b  = (const float*)d_in[3];
  const float* out_w  = (const float*)d_in[4];
  const float* out_b  = (const float*)d_in[5];
  const float* sinks  = (const float*)d_in[6];
  float* out = (float*)d_out;
  int n = in_sizes[0] / HIDDEN;  // 1536

  char* ws = (char*)d_ws;
  size_t off = 0;
  auto alloc = [&](size_t bytes) {
    char* p = ws + off;
    off += (bytes + 255) & ~(size_t)255;
    return p;
  };
  ushort* t_bf    = (ushort*)alloc((size_t)n * HIDDEN * 2);
  ushort* qkvw_bf = (ushort*)alloc((size_t)QKV_DIM * HIDDEN * 2);
  ushort* outw_bf = (ushort*)alloc((size_t)HIDDEN * ATT_DIM * 2);
  ushort* qkv_bf  = (ushort*)alloc((size_t)n * QKV_DIM * 2);   // biased bf16 qkv
  ushort* q_bf    = (ushort*)alloc((size_t)n * NH * HD * 2);
  ushort* k_bf    = (ushort*)alloc((size_t)n * NKV * HD * 2);
  ushort* v_bf    = (ushort*)alloc((size_t)n * NKV * HD * 2);
  ushort* attn    = (ushort*)alloc((size_t)n * ATT_DIM * 2);
  size_t out_ps = (size_t)n * HIDDEN;
  ushort* partials = (ushort*)alloc(2 * out_ps * 2);

  // fused rmsnorm (n blocks) + qkv_w cvt (1024 blocks)
  norm_cvt<<<n + 1024, 256, 0, stream>>>(x, nscale, t_bf, n,
                                         qkv_w, qkvw_bf, QKV_DIM * HIDDEN / 4);
  // QKV: M=1536 N=5120 K=2880, 128^2 tiles -> 12x40 = 480 wg (~1.9/CU), NO split-K;
  // bias fused, writes biased bf16 qkv directly.
  gemm_128<0, 1><<<dim3((n / 128) * (QKV_DIM / 128), 1), 256, 0, stream>>>(
      t_bf, qkvw_bf, qkv_b, qkv_bf, n, QKV_DIM, HIDDEN, 1);
  rope_split<<<n, 256, 0, stream>>>(qkv_bf, q_bf, k_bf, v_bf);
  // attention (768 blocks) + hidden out_w cvt (320 blocks)
  int nattn = (n / 16) * NKV;
  attn_cvt<<<nattn + 320, 512, 0, stream>>>(q_bf, k_bf, v_bf, sinks, attn, n, nattn,
                                            out_w, outw_bf, HIDDEN * ATT_DIM / 4);
  // out: M=1536 N=2880 K=4096, 128^2 tiles -> 12x23 = 276 wg, split-K x2 -> 552 wg
  gemm_128<1, 0><<<dim3((n / 128) * 23, 2), 256, 0, stream>>>(
      attn, outw_bf, nullptr, partials, n, HIDDEN, ATT_DIM, 2);
  reduce_out<<<(n * HIDDEN / 4 + 255) / 256, 256, 0, stream>>>(
      x, out_b, partials, 2, out_ps, out, n * HIDDEN / 4, HIDDEN);
}

// Round 13
// 194.834 us; speedup vs baseline: 1.0421x; 1.0421x over previous
//
#include <hip/hip_runtime.h>

typedef __attribute__((ext_vector_type(8))) short bf16x8;
typedef __attribute__((ext_vector_type(4))) float f32x4;

#define HIDDEN 2880
#define QKV_DIM 5120
#define NH 64
#define NKV 8
#define HD 64
#define ATT_DIM 4096
#define WINDOW 128
#define SM_SCALE 0.125f

__device__ __forceinline__ ushort f2bf(float f) {
  union { float f; unsigned u; } a; a.f = f;
  unsigned r = a.u + 0x7fffu + ((a.u >> 16) & 1u);
  return (ushort)(r >> 16);
}
__device__ __forceinline__ float bf2f(ushort u) {
  union { unsigned u; float f; } a; a.u = ((unsigned)u) << 16;
  return a.f;
}

__device__ __forceinline__ void gload_lds16(const void* g, void* l) {
  __builtin_amdgcn_global_load_lds((const __attribute__((address_space(1))) void*)g,
                                   (__attribute__((address_space(3))) void*)l, 16, 0, 0);
}

// ------- fused: RMSNorm (blocks [0,n)) + qkv_w f32->bf16 cvt (blocks [n, n+1024)) -------
__global__ __launch_bounds__(256)
void norm_cvt(const float* __restrict__ x, const float* __restrict__ scale,
              ushort* __restrict__ t, int n,
              const float* __restrict__ w, ushort* __restrict__ wout, int n4w) {
  int tid = threadIdx.x;
  if ((int)blockIdx.x >= n) {
    int i = ((int)blockIdx.x - n) * 256 + tid;
    int stride = (gridDim.x - n) * 256;
    for (; i < n4w; i += stride) {
      float4 v = ((const float4*)w)[i];
      ushort4 o = { f2bf(v.x), f2bf(v.y), f2bf(v.z), f2bf(v.w) };
      ((ushort4*)wout)[i] = o;
    }
    return;
  }
  int row = blockIdx.x;
  const float4* xr = (const float4*)(x + (size_t)row * HIDDEN);
  float4 a0 = xr[tid];
  float4 a1 = xr[tid + 256];
  bool has2 = tid < 208;
  float4 a2 = has2 ? xr[tid + 512] : float4{0.f, 0.f, 0.f, 0.f};
  float ss = a0.x*a0.x + a0.y*a0.y + a0.z*a0.z + a0.w*a0.w
           + a1.x*a1.x + a1.y*a1.y + a1.z*a1.z + a1.w*a1.w
           + a2.x*a2.x + a2.y*a2.y + a2.z*a2.z + a2.w*a2.w;
  for (int m = 1; m < 64; m <<= 1) ss += __shfl_xor(ss, m, 64);
  __shared__ float red[4];
  if ((tid & 63) == 0) red[tid >> 6] = ss;
  __syncthreads();
  ss = red[0] + red[1] + red[2] + red[3];
  float r = rsqrtf(ss / (float)HIDDEN + 1e-5f);
  ushort4* tr = (ushort4*)(t + (size_t)row * HIDDEN);
  const float4* sc4 = (const float4*)scale;
  {
    float4 s = sc4[tid];
    ushort4 o = { f2bf(a0.x*r*s.x), f2bf(a0.y*r*s.y), f2bf(a0.z*r*s.z), f2bf(a0.w*r*s.w) };
    tr[tid] = o;
  }
  {
    float4 s = sc4[tid + 256];
    ushort4 o = { f2bf(a1.x*r*s.x), f2bf(a1.y*r*s.y), f2bf(a1.z*r*s.z), f2bf(a1.w*r*s.w) };
    tr[tid + 256] = o;
  }
  if (has2) {
    float4 s = sc4[tid + 512];
    ushort4 o = { f2bf(a2.x*r*s.x), f2bf(a2.y*r*s.y), f2bf(a2.z*r*s.z), f2bf(a2.w*r*s.w) };
    tr[tid + 512] = o;
  }
}

// -------- 256x(64*NFRAG) 8-phase pipelined bf16 GEMM (split-K), R7-proven schedule --------
// 8 waves (2M x 4N), per-wave 128 x 16*NFRAG. NFRAG=4: BN=256 (QKV, 5120=20x256 exact);
// NFRAG=3: BN=192 (out, 2880=15x192 exact). No masks anywhere.
// Race mapping (proven R7): A regions r0,r2 read only P1 -> staged P2; r1,r3 read only
// P3 -> staged P4; ALL B reads done by P2-end -> all B staged P3. Counted vmcnt(4+NFRAG)
// per tile (one tile's stage instrs/wave in flight), never 0 in steady state.
template <int NFRAG>
__global__ __launch_bounds__(512)
void gemm_8p(const ushort* __restrict__ A, const ushort* __restrict__ B,
             ushort* __restrict__ P, int M, int N, int K, int NSK) {
  constexpr int N1 = NFRAG - 2;           // frags in the "hi" B quadrant
  __shared__ __align__(16) ushort Al[2][256 * 64];
  __shared__ __align__(16) ushort Bl[2][NFRAG * 64 * 64];
  const int tid = threadIdx.x;
  const int wave = tid >> 6, lane = tid & 63;
  const int l15 = lane & 15, hi = lane >> 4;

  int nwg = gridDim.x, orig = blockIdx.x;
  int q8 = nwg >> 3, r8 = nwg & 7, xcd = orig & 7, seq = orig >> 3;
  int swz = (xcd < r8 ? xcd * (q8 + 1) : r8 * (q8 + 1) + (xcd - r8) * q8) + seq;
  int nm = M >> 8;
  int bm = swz % nm, bn = swz / nm;
  const int row0 = bm * 256, col0 = bn * (64 * NFRAG);
  const int sk = blockIdx.y;
  const int NTtot = K >> 6;
  const int tt0 = sk * NTtot / NSK, tt1 = (sk + 1) * NTtot / NSK;
  ushort* Pp = P + (size_t)sk * M * N;

  const int wrow = (wave >> 2) * 128;
  const int wcol = (wave & 3) * (16 * NFRAG);
  const int srow = lane >> 3;
  const int schunk = (lane & 7) ^ srow;

  f32x4 acc[8][NFRAG] = {};

  auto stageA = [&](int t, int r) {
    int row = row0 + r * 64 + wave * 8 + srow;
    gload_lds16(A + (size_t)row * K + (t << 6) + schunk * 8,
                &Al[t & 1][(r * 64 + wave * 8) * 64]);
  };
  auto stageB = [&](int t, int r) {
    int brow = col0 + r * 64 + wave * 8 + srow;
    gload_lds16(B + (size_t)brow * K + (t << 6) + schunk * 8,
                &Bl[t & 1][(r * 64 + wave * 8) * 64]);
  };
  auto stageAll = [&](int t) {
#pragma unroll
    for (int r = 0; r < 4; ++r) stageA(t, r);
#pragma unroll
    for (int r = 0; r < NFRAG; ++r) stageB(t, r);
  };
  auto LDA = [&](bf16x8 (&dst)[4][2], int mh, const char* base) {
#pragma unroll
    for (int mt = 0; mt < 4; ++mt)
#pragma unroll
      for (int ks = 0; ks < 2; ++ks) {
        int rr = wrow + mh * 64 + mt * 16 + l15;
        int off = (rr * 128 + ks * 64 + hi * 16) ^ ((rr & 7) << 4);
        dst[mt][ks] = *(const bf16x8*)(base + off);
      }
  };
  auto LDB_lo = [&](bf16x8 (&dst)[2][2], const char* base) {
#pragma unroll
    for (int nt = 0; nt < 2; ++nt)
#pragma unroll
      for (int ks = 0; ks < 2; ++ks) {
        int rr = wcol + nt * 16 + l15;
        int off = (rr * 128 + ks * 64 + hi * 16) ^ ((rr & 7) << 4);
        dst[nt][ks] = *(const bf16x8*)(base + off);
      }
  };
  auto LDB_hi = [&](bf16x8 (&dst)[2][2], const char* base) {
#pragma unroll
    for (int nt = 0; nt < N1; ++nt)
#pragma unroll
      for (int ks = 0; ks < 2; ++ks) {
        int rr = wcol + (2 + nt) * 16 + l15;
        int off = (rr * 128 + ks * 64 + hi * 16) ^ ((rr & 7) << 4);
        dst[nt][ks] = *(const bf16x8*)(base + off);
      }
  };
  auto MMA_lo = [&](bf16x8 (&a)[4][2], bf16x8 (&b)[2][2], int mh) {
    __builtin_amdgcn_s_setprio(1);
#pragma unroll
    for (int ks = 0; ks < 2; ++ks)
#pragma unroll
      for (int nt = 0; nt < 2; ++nt)
#pragma unroll
        for (int mt = 0; mt < 4; ++mt)
          acc[mh * 4 + mt][nt] = __builtin_amdgcn_mfma_f32_16x16x32_bf16(
              a[mt][ks], b[nt][ks], acc[mh * 4 + mt][nt], 0, 0, 0);
    __builtin_amdgcn_s_setprio(0);
  };
  auto MMA_hi = [&](bf16x8 (&a)[4][2], bf16x8 (&b)[2][2], int mh) {
    __builtin_amdgcn_s_setprio(1);
#pragma unroll
    for (int ks = 0; ks < 2; ++ks)
#pragma unroll
      for (int nt = 0; nt < N1; ++nt)
#pragma unroll
        for (int mt = 0; mt < 4; ++mt)
          acc[mh * 4 + mt][2 + nt] = __builtin_amdgcn_mfma_f32_16x16x32_bf16(
              a[mt][ks], b[nt][ks], acc[mh * 4 + mt][2 + nt], 0, 0, 0);
    __builtin_amdgcn_s_setprio(0);
  };

  stageAll(tt0);
  bool two = (tt1 - tt0 > 1);
  if (two) {
    stageAll(tt0 + 1);
    if constexpr (NFRAG == 4) asm volatile("s_waitcnt vmcnt(8)" ::: "memory");
    else                      asm volatile("s_waitcnt vmcnt(7)" ::: "memory");
  } else {
    asm volatile("s_waitcnt vmcnt(0)" ::: "memory");
  }
  __builtin_amdgcn_s_barrier();

  for (int t = tt0; t < tt1; ++t) {
    const char* Ab = (const char*)&Al[t & 1][0];
    const char* Bb = (const char*)&Bl[t & 1][0];
    bool pre = (t + 2 < tt1);
    bf16x8 afr[4][2], bf0[2][2], bf1[2][2];
    // P1
    LDA(afr, 0, Ab);
    LDB_lo(bf0, Bb);
    __builtin_amdgcn_s_barrier();
    MMA_lo(afr, bf0, 0);
    __builtin_amdgcn_s_barrier();
    // P2
    LDB_hi(bf1, Bb);
    if (pre) { stageA(t + 2, 0); stageA(t + 2, 2); }
    __builtin_amdgcn_s_barrier();
    MMA_hi(afr, bf1, 0);
    __builtin_amdgcn_s_barrier();
    // P3 (all B LDS reads of this buffer are done by P2-end)
    LDA(afr, 1, Ab);
    if (pre) {
#pragma unroll
      for (int r = 0; r < NFRAG; ++r) stageB(t + 2, r);
    }
    __builtin_amdgcn_s_barrier();
    MMA_hi(afr, bf1, 1);
    __builtin_amdgcn_s_barrier();
    // P4
    if (pre) { stageA(t + 2, 1); stageA(t + 2, 3); }
    __builtin_amdgcn_s_barrier();
    MMA_lo(afr, bf0, 1);
    if (pre) {
      if constexpr (NFRAG == 4) asm volatile("s_waitcnt vmcnt(8)" ::: "memory");
      else                      asm volatile("s_waitcnt vmcnt(7)" ::: "memory");
    } else {
      asm volatile("s_waitcnt vmcnt(0)" ::: "memory");
    }
    __builtin_amdgcn_s_barrier();
  }

  // epilogue: C/D layout col=lane&15, row=(lane>>4)*4+r (m89-verified); bf16 partials
#pragma unroll
  for (int mtg = 0; mtg < 8; ++mtg) {
#pragma unroll
    for (int nt = 0; nt < NFRAG; ++nt) {
#pragma unroll
      for (int rr = 0; rr < 4; ++rr) {
        int row = row0 + wrow + mtg * 16 + (hi << 2) + rr;
        int col = col0 + wcol + nt * 16 + l15;
        Pp[(size_t)row * N + col] = f2bf(acc[mtg][nt][rr]);
      }
    }
  }
}

// ---------------- out reduce: out = x + out_b + sum_sk bf16 partials ----------------
__global__ __launch_bounds__(256)
void reduce_out(const float* __restrict__ x, const float* __restrict__ b,
                const ushort* __restrict__ p, int nsk, size_t stride,
                float* __restrict__ out, int n4, int N) {
  int i = blockIdx.x * blockDim.x + threadIdx.x;
  if (i >= n4) return;
  float4 v = ((const float4*)x)[i];
  int col = (i * 4) % N;
  float4 bb = *(const float4*)(b + col);
  v.x += bb.x; v.y += bb.y; v.z += bb.z; v.w += bb.w;
  for (int s = 0; s < nsk; ++s) {
    ushort4 pv = *(const ushort4*)(p + s * stride + (size_t)i * 4);
    v.x += bf2f(pv.x); v.y += bf2f(pv.y); v.z += bf2f(pv.z); v.w += bf2f(pv.w);
  }
  ((float4*)out)[i] = v;
}

// ---------------- RoPE + qkv split-K reduce (bf16 partials) + bias + split ----------------
__global__ __launch_bounds__(256)
void rope_split(const ushort* __restrict__ p, size_t stride, const float* __restrict__ qkvb,
                ushort* __restrict__ qb, ushort* __restrict__ kb, ushort* __restrict__ vb) {
  int tok = blockIdx.x;
  int tid = threadIdx.x;
  __shared__ float cs[32], sn[32];
  if (tid < 32) {
    float d = (float)tid;
    float freq = powf(150000.0f, d / 32.0f);
    float conc = 0.1f * logf(32.0f) + 1.0f;
    float lg = logf(150000.0f);
    float low = 32.0f * logf(4096.0f / (32.0f * 6.2831853f)) / lg;
    float high = 32.0f * logf(4096.0f / 6.2831853f) / lg;
    float ramp = (d - low) / (high - low);
    float cl = fminf(fmaxf(ramp, 0.0f), 1.0f);
    float mask = 1.0f - cl;
    float inv_freq = (1.0f - mask) / (32.0f * freq) + mask / freq;
    float fr = (float)tok * inv_freq;
    cs[tid] = cosf(fr) * conc;
    sn[tid] = sinf(fr) * conc;
  }
  __syncthreads();
  const ushort* r0 = p + (size_t)tok * QKV_DIM;
  const ushort* r1 = r0 + stride;
  auto ld = [&](int c) { return bf2f(r0[c]) + bf2f(r1[c]) + qkvb[c]; };
#pragma unroll
  for (int it = 0; it < 8; ++it) {
    int pp = tid + it * 256;
    int hd = pp >> 5, d = pp & 31;
    float x1 = ld(hd * 64 + d), x2 = ld(hd * 64 + d + 32);
    float c = cs[d], s = sn[d];
    size_t o = ((size_t)tok * NH + hd) * HD + d;
    qb[o] = f2bf(x1 * c - x2 * s);
    qb[o + 32] = f2bf(x2 * c + x1 * s);
  }
  {
    int pp = tid;
    int hd = pp >> 5, d = pp & 31;
    float x1 = ld(4096 + hd * 64 + d), x2 = ld(4096 + hd * 64 + d + 32);
    float c = cs[d], s = sn[d];
    size_t o = ((size_t)tok * NKV + hd) * HD + d;
    kb[o] = f2bf(x1 * c - x2 * s);
    kb[o + 32] = f2bf(x2 * c + x1 * s);
  }
#pragma unroll
  for (int it = 0; it < 2; ++it) {
    int pp = tid + it * 256;
    vb[(size_t)tok * (NKV * HD) + pp] = f2bf(ld(4608 + pp));
  }
}

// ---- attention (sliding window 128 + sink, 16 q/wave) + hidden out_w f32->bf16 cvt ----
__global__ __launch_bounds__(512)
void attn_cvt(const ushort* __restrict__ qb, const ushort* __restrict__ kb,
              const ushort* __restrict__ vb, const float* __restrict__ sinks,
              ushort* __restrict__ attn, int n, int nattn,
              const float* __restrict__ w, ushort* __restrict__ wout, int n4w) {
  __shared__ __align__(16) ushort Kl[160 * 64];
  __shared__ __align__(16) ushort Vt[64 * 168];
  __shared__ __align__(16) ushort Pl[8][16 * 40];
  int tid = threadIdx.x;
  if ((int)blockIdx.x >= nattn) {
    int i = ((int)blockIdx.x - nattn) * 512 + tid;
    int stride = (gridDim.x - nattn) * 512;
    for (; i < n4w; i += stride) {
      float4 v = ((const float4*)w)[i];
      ushort4 o = { f2bf(v.x), f2bf(v.y), f2bf(v.z), f2bf(v.w) };
      ((ushort4*)wout)[i] = o;
    }
    return;
  }
  int wave = tid >> 6, lane = tid & 63;
  int l15 = lane & 15, hi = lane >> 4;
  int qstart = ((int)blockIdx.x >> 3) * 16;
  int kv = (int)blockIdx.x & 7;
  int head = kv * 8 + wave;
  int key0 = qstart - 128;

  for (int i = 0; i < 3; ++i) {
    int rowb = i * 64 + wave * 8;
    if (rowb < 160) {
      int r = rowb + (lane >> 3);
      int gj = key0 + r; if (gj < 0) gj = 0;
      int chunk = (lane & 7) ^ (lane >> 3);
      gload_lds16(kb + ((size_t)gj * NKV + kv) * HD + chunk * 8, Kl + rowb * 64);
    }
  }
  for (int e = tid; e < 160 * 16; e += 512) {
    int j = e >> 4, d4 = (e & 15) << 2;
    int gj = key0 + j; if (gj < 0) gj = 0;
    ushort4 v = *(const ushort4*)(vb + ((size_t)gj * NKV + kv) * HD + d4);
    Vt[(d4 + 0) * 168 + j] = v.x;
    Vt[(d4 + 1) * 168 + j] = v.y;
    Vt[(d4 + 2) * 168 + j] = v.z;
    Vt[(d4 + 3) * 168 + j] = v.w;
  }
  bf16x8 qf[2];
#pragma unroll
  for (int ks = 0; ks < 2; ++ks) {
    int r = qstart + l15;
    int kk = ks * 32 + hi * 8;
    qf[ks] = *(const bf16x8*)(qb + ((size_t)r * NH + head) * HD + kk);
  }
  __syncthreads();

  f32x4 s[10] = {};
#pragma unroll
  for (int nt = 0; nt < 10; ++nt) {
#pragma unroll
    for (int ks = 0; ks < 2; ++ks) {
      int r = nt * 16 + l15;
      int off = (r * 128 + (ks * 32 + hi * 8) * 2) ^ ((r & 7) << 4);
      bf16x8 kf = *(const bf16x8*)((const char*)Kl + off);
      s[nt] = __builtin_amdgcn_mfma_f32_16x16x32_bf16(qf[ks], kf, s[nt], 0, 0, 0);
    }
  }

  float lrow[4];
  float snk = sinks[head];
#pragma unroll
  for (int r = 0; r < 4; ++r) {
    int i = qstart + hi * 4 + r;
    float mx = -1e30f;
#pragma unroll
    for (int nt = 0; nt < 10; ++nt) {
      int j = key0 + nt * 16 + l15;
      bool ok = (j >= 0) && (j <= i) && (j > i - WINDOW);
      float val = ok ? s[nt][r] * SM_SCALE : -1e30f;
      s[nt][r] = val;
      mx = fmaxf(mx, val);
    }
    mx = fmaxf(mx, __shfl_xor(mx, 1, 64));
    mx = fmaxf(mx, __shfl_xor(mx, 2, 64));
    mx = fmaxf(mx, __shfl_xor(mx, 4, 64));
    mx = fmaxf(mx, __shfl_xor(mx, 8, 64));
    mx = fmaxf(mx, snk);
    float sum = 0.f;
#pragma unroll
    for (int nt = 0; nt < 10; ++nt) {
      float pv = __expf(s[nt][r] - mx);
      s[nt][r] = pv;
      sum += pv;
    }
    sum += __shfl_xor(sum, 1, 64);
    sum += __shfl_xor(sum, 2, 64);
    sum += __shfl_xor(sum, 4, 64);
    sum += __shfl_xor(sum, 8, 64);
    sum += __expf(snk - mx);
    lrow[r] = sum;
  }

  f32x4 o[4] = {};
#pragma unroll
  for (int kc = 0; kc < 5; ++kc) {
#pragma unroll
    for (int t2 = 0; t2 < 2; ++t2) {
      int nt = kc * 2 + t2;
#pragma unroll
      for (int r = 0; r < 4; ++r)
        Pl[wave][(hi * 4 + r) * 40 + t2 * 16 + l15] = f2bf(s[nt][r]);
    }
    bf16x8 pa = *(const bf16x8*)(&Pl[wave][l15 * 40 + hi * 8]);
#pragma unroll
    for (int nt = 0; nt < 4; ++nt) {
      int d = nt * 16 + l15;
      int kk = kc * 32 + hi * 8;
      bf16x8 vf = *(const bf16x8*)(&Vt[d * 168 + kk]);
      o[nt] = __builtin_amdgcn_mfma_f32_16x16x32_bf16(pa, vf, o[nt], 0, 0, 0);
    }
  }

#pragma unroll
  for (int nt = 0; nt < 4; ++nt)
#pragma unroll
    for (int r = 0; r < 4; ++r) {
      int row = qstart + hi * 4 + r;
      int d = nt * 16 + l15;
      float val = o[nt][r] / lrow[r];
      attn[((size_t)row * NH + head) * HD + d] = f2bf(val);
    }
}

extern "C" void kernel_launch(void* const* d_in, const int* in_sizes, int n_in,
                              void* d_out, int out_size, void* d_ws, size_t ws_size,
                              hipStream_t stream) {
  const float* x      = (const float*)d_in[0];
  const float* nscale = (const float*)d_in[1];
  const float* qkv_w  = (const float*)d_in[2];
  const float* qkv_b  = (const float*)d_in[3];
  const float* out_w  = (const float*)d_in[4];
  const float* out_b  = (const float*)d_in[5];
  const float* sinks  = (const float*)d_in[6];
  float* out = (float*)d_out;
  int n = in_sizes[0] / HIDDEN;  // 1536

  char* ws = (char*)d_ws;
  size_t off = 0;
  auto alloc = [&](size_t bytes) {
    char* p = ws + off;
    off += (bytes + 255) & ~(size_t)255;
    return p;
  };
  ushort* t_bf    = (ushort*)alloc((size_t)n * HIDDEN * 2);
  ushort* qkvw_bf = (ushort*)alloc((size_t)QKV_DIM * HIDDEN * 2);
  ushort* outw_bf = (ushort*)alloc((size_t)HIDDEN * ATT_DIM * 2);
  ushort* q_bf    = (ushort*)alloc((size_t)n * NH * HD * 2);
  ushort* k_bf    = (ushort*)alloc((size_t)n * NKV * HD * 2);
  ushort* v_bf    = (ushort*)alloc((size_t)n * NKV * HD * 2);
  ushort* attn    = (ushort*)alloc((size_t)n * ATT_DIM * 2);
  size_t qkv_ps = (size_t)n * QKV_DIM;   // elements per qkv partial slice
  size_t out_ps = (size_t)n * HIDDEN;    // elements per out partial slice
  size_t pelems = 2 * qkv_ps > 3 * out_ps ? 2 * qkv_ps : 3 * out_ps;
  ushort* partials = (ushort*)alloc(pelems * 2);

  // fused rmsnorm (n blocks) + qkv_w cvt (1024 blocks)
  norm_cvt<<<n + 1024, 256, 0, stream>>>(x, nscale, t_bf, n,
                                         qkv_w, qkvw_bf, QKV_DIM * HIDDEN / 4);
  // QKV: M=1536 N=5120 K=2880, 256x256 tiles -> 6x20=120 wg, split-K x2 -> 240 wg (exact)
  gemm_8p<4><<<dim3((n / 256) * (QKV_DIM / 256), 2), 512, 0, stream>>>(
      t_bf, qkvw_bf, partials, n, QKV_DIM, HIDDEN, 2);
  rope_split<<<n, 256, 0, stream>>>(partials, qkv_ps, qkv_b, q_bf, k_bf, v_bf);
  // attention (768 blocks) + hidden out_w cvt (320 blocks)
  int nattn = (n / 16) * NKV;
  attn_cvt<<<nattn + 320, 512, 0, stream>>>(q_bf, k_bf, v_bf, sinks, attn, n, nattn,
                                            out_w, outw_bf, HIDDEN * ATT_DIM / 4);
  // out: M=1536 N=2880 K=4096, 256x192 tiles -> 6x15=90 wg, split-K x3 -> 270 wg (exact)
  gemm_8p<3><<<dim3((n / 256) * (HIDDEN / 192), 3), 512, 0, stream>>>(
      attn, outw_bf, partials, n, HIDDEN, ATT_DIM, 3);
  reduce_out<<<(n * HIDDEN / 4 + 255) / 256, 256, 0, stream>>>(
      x, out_b, partials, 3, out_ps, out, n * HIDDEN / 4, HIDDEN);
}

// Round 14
// 171.089 us; speedup vs baseline: 1.1868x; 1.1388x over previous
//
#include <hip/hip_runtime.h>

typedef __attribute__((ext_vector_type(8))) short bf16x8;
typedef __attribute__((ext_vector_type(4))) float f32x4;

#define HIDDEN 2880
#define QKV_DIM 5120
#define NH 64
#define NKV 8
#define HD 64
#define ATT_DIM 4096
#define WINDOW 128
#define SM_SCALE 0.125f

__device__ __forceinline__ ushort f2bf(float f) {
  union { float f; unsigned u; } a; a.f = f;
  unsigned r = a.u + 0x7fffu + ((a.u >> 16) & 1u);
  return (ushort)(r >> 16);
}
__device__ __forceinline__ float bf2f(ushort u) {
  union { unsigned u; float f; } a; a.u = ((unsigned)u) << 16;
  return a.f;
}

__device__ __forceinline__ void gload_lds16(const void* g, void* l) {
  __builtin_amdgcn_global_load_lds((const __attribute__((address_space(1))) void*)g,
                                   (__attribute__((address_space(3))) void*)l, 16, 0, 0);
}

// ------- fused: RMSNorm (blocks [0,n)) + qkv_w f32->bf16 cvt (blocks [n, n+1024)) -------
__global__ __launch_bounds__(256)
void norm_cvt(const float* __restrict__ x, const float* __restrict__ scale,
              ushort* __restrict__ t, int n,
              const float* __restrict__ w, ushort* __restrict__ wout, int n4w) {
  int tid = threadIdx.x;
  if ((int)blockIdx.x >= n) {
    int i = ((int)blockIdx.x - n) * 256 + tid;
    int stride = (gridDim.x - n) * 256;
    for (; i < n4w; i += stride) {
      float4 v = ((const float4*)w)[i];
      ushort4 o = { f2bf(v.x), f2bf(v.y), f2bf(v.z), f2bf(v.w) };
      ((ushort4*)wout)[i] = o;
    }
    return;
  }
  int row = blockIdx.x;
  const float4* xr = (const float4*)(x + (size_t)row * HIDDEN);
  float4 a0 = xr[tid];
  float4 a1 = xr[tid + 256];
  bool has2 = tid < 208;
  float4 a2 = has2 ? xr[tid + 512] : float4{0.f, 0.f, 0.f, 0.f};
  float ss = a0.x*a0.x + a0.y*a0.y + a0.z*a0.z + a0.w*a0.w
           + a1.x*a1.x + a1.y*a1.y + a1.z*a1.z + a1.w*a1.w
           + a2.x*a2.x + a2.y*a2.y + a2.z*a2.z + a2.w*a2.w;
  for (int m = 1; m < 64; m <<= 1) ss += __shfl_xor(ss, m, 64);
  __shared__ float red[4];
  if ((tid & 63) == 0) red[tid >> 6] = ss;
  __syncthreads();
  ss = red[0] + red[1] + red[2] + red[3];
  float r = rsqrtf(ss / (float)HIDDEN + 1e-5f);
  ushort4* tr = (ushort4*)(t + (size_t)row * HIDDEN);
  const float4* sc4 = (const float4*)scale;
  {
    float4 s = sc4[tid];
    ushort4 o = { f2bf(a0.x*r*s.x), f2bf(a0.y*r*s.y), f2bf(a0.z*r*s.z), f2bf(a0.w*r*s.w) };
    tr[tid] = o;
  }
  {
    float4 s = sc4[tid + 256];
    ushort4 o = { f2bf(a1.x*r*s.x), f2bf(a1.y*r*s.y), f2bf(a1.z*r*s.z), f2bf(a1.w*r*s.w) };
    tr[tid + 256] = o;
  }
  if (has2) {
    float4 s = sc4[tid + 512];
    ushort4 o = { f2bf(a2.x*r*s.x), f2bf(a2.y*r*s.y), f2bf(a2.z*r*s.z), f2bf(a2.w*r*s.w) };
    tr[tid + 512] = o;
  }
}

// -------- 256x256 8-phase pipelined bf16 GEMM (split-K): P[sk] = A * B^T K-slice --------
// EXACT R7/R11 schedule (best measured: ~64.5us, MfmaUtil ~22.7%). bf16 partials.
template <int MASK_N>
__global__ __launch_bounds__(512)
void gemm_8p(const ushort* __restrict__ A, const ushort* __restrict__ B,
             ushort* __restrict__ P, int M, int N, int K, int NSK) {
  __shared__ __align__(16) ushort Al[2][256 * 64];
  __shared__ __align__(16) ushort Bl[2][256 * 64];
  const int tid = threadIdx.x;
  const int wave = tid >> 6, lane = tid & 63;
  const int l15 = lane & 15, hi = lane >> 4;

  int nwg = gridDim.x, orig = blockIdx.x;
  int q8 = nwg >> 3, r8 = nwg & 7, xcd = orig & 7, seq = orig >> 3;
  int swz = (xcd < r8 ? xcd * (q8 + 1) : r8 * (q8 + 1) + (xcd - r8) * q8) + seq;
  int nm = M >> 8;
  int bm = swz % nm, bn = swz / nm;
  const int row0 = bm * 256, col0 = bn * 256;
  const int sk = blockIdx.y;
  const int NTtot = K >> 6;
  const int tt0 = sk * NTtot / NSK, tt1 = (sk + 1) * NTtot / NSK;
  ushort* Pp = P + (size_t)sk * M * N;

  const int wrow = (wave >> 2) * 128;
  const int wcol = (wave & 3) * 64;
  const int srow = lane >> 3;
  const int schunk = (lane & 7) ^ srow;

  f32x4 acc[8][4] = {};

  auto stageA = [&](int t, int r) {
    int row = row0 + r * 64 + wave * 8 + srow;
    gload_lds16(A + (size_t)row * K + (t << 6) + schunk * 8,
                &Al[t & 1][(r * 64 + wave * 8) * 64]);
  };
  auto stageB = [&](int t, int r) {
    int brow = col0 + r * 64 + wave * 8 + srow;
    if (MASK_N) { if (brow > N - 1) brow = N - 1; }
    gload_lds16(B + (size_t)brow * K + (t << 6) + schunk * 8,
                &Bl[t & 1][(r * 64 + wave * 8) * 64]);
  };
  auto stageAll = [&](int t) {
#pragma unroll
    for (int r = 0; r < 4; ++r) { stageA(t, r); stageB(t, r); }
  };
  auto LDA = [&](bf16x8 (&dst)[4][2], int mh, const char* base) {
#pragma unroll
    for (int mt = 0; mt < 4; ++mt)
#pragma unroll
      for (int ks = 0; ks < 2; ++ks) {
        int rr = wrow + mh * 64 + mt * 16 + l15;
        int off = (rr * 128 + ks * 64 + hi * 16) ^ ((rr & 7) << 4);
        dst[mt][ks] = *(const bf16x8*)(base + off);
      }
  };
  auto LDB = [&](bf16x8 (&dst)[2][2], int nh, const char* base) {
#pragma unroll
    for (int nt = 0; nt < 2; ++nt)
#pragma unroll
      for (int ks = 0; ks < 2; ++ks) {
        int rr = wcol + nh * 32 + nt * 16 + l15;
        int off = (rr * 128 + ks * 64 + hi * 16) ^ ((rr & 7) << 4);
        dst[nt][ks] = *(const bf16x8*)(base + off);
      }
  };
  auto MMA = [&](bf16x8 (&a)[4][2], bf16x8 (&b)[2][2], int mh, int nh) {
    __builtin_amdgcn_s_setprio(1);
#pragma unroll
    for (int ks = 0; ks < 2; ++ks)
#pragma unroll
      for (int nt = 0; nt < 2; ++nt)
#pragma unroll
        for (int mt = 0; mt < 4; ++mt)
          acc[mh * 4 + mt][nh * 2 + nt] = __builtin_amdgcn_mfma_f32_16x16x32_bf16(
              a[mt][ks], b[nt][ks], acc[mh * 4 + mt][nh * 2 + nt], 0, 0, 0);
    __builtin_amdgcn_s_setprio(0);
  };

  stageAll(tt0);
  bool two = (tt1 - tt0 > 1);
  if (two) {
    stageAll(tt0 + 1);
    asm volatile("s_waitcnt vmcnt(8)" ::: "memory");
  } else {
    asm volatile("s_waitcnt vmcnt(0)" ::: "memory");
  }
  __builtin_amdgcn_s_barrier();

  for (int t = tt0; t < tt1; ++t) {
    const char* Ab = (const char*)&Al[t & 1][0];
    const char* Bb = (const char*)&Bl[t & 1][0];
    bool pre = (t + 2 < tt1);
    bf16x8 afr[4][2], bf0[2][2], bf1[2][2];
    // P1
    LDA(afr, 0, Ab);
    LDB(bf0, 0, Bb);
    __builtin_amdgcn_s_barrier();
    MMA(afr, bf0, 0, 0);
    __builtin_amdgcn_s_barrier();
    // P2
    LDB(bf1, 1, Bb);
    if (pre) { stageA(t + 2, 0); stageA(t + 2, 2); }
    __builtin_amdgcn_s_barrier();
    MMA(afr, bf1, 0, 1);
    __builtin_amdgcn_s_barrier();
    // P3
    LDA(afr, 1, Ab);
    if (pre) { stageB(t + 2, 0); stageB(t + 2, 1); stageB(t + 2, 2); stageB(t + 2, 3); }
    __builtin_amdgcn_s_barrier();
    MMA(afr, bf1, 1, 1);
    __builtin_amdgcn_s_barrier();
    // P4
    if (pre) { stageA(t + 2, 1); stageA(t + 2, 3); }
    __builtin_amdgcn_s_barrier();
    MMA(afr, bf0, 1, 0);
    if (pre) asm volatile("s_waitcnt vmcnt(8)" ::: "memory");
    else     asm volatile("s_waitcnt vmcnt(0)" ::: "memory");
    __builtin_amdgcn_s_barrier();
  }

  // epilogue: C/D layout col=lane&15, row=(lane>>4)*4+r (m89-verified); bf16 partials
#pragma unroll
  for (int mtg = 0; mtg < 8; ++mtg) {
#pragma unroll
    for (int nt = 0; nt < 4; ++nt) {
#pragma unroll
      for (int rr = 0; rr < 4; ++rr) {
        int row = row0 + wrow + mtg * 16 + (hi << 2) + rr;
        int col = col0 + wcol + nt * 16 + l15;
        if (!MASK_N || col < N) Pp[(size_t)row * N + col] = f2bf(acc[mtg][nt][rr]);
      }
    }
  }
}

// ---------------- out reduce: out = x + out_b + sum_sk bf16 partials ----------------
__global__ __launch_bounds__(256)
void reduce_out(const float* __restrict__ x, const float* __restrict__ b,
                const ushort* __restrict__ p, int nsk, size_t stride,
                float* __restrict__ out, int n4, int N) {
  int i = blockIdx.x * blockDim.x + threadIdx.x;
  if (i >= n4) return;
  float4 v = ((const float4*)x)[i];
  int col = (i * 4) % N;
  float4 bb = *(const float4*)(b + col);
  v.x += bb.x; v.y += bb.y; v.z += bb.z; v.w += bb.w;
  for (int s = 0; s < nsk; ++s) {
    ushort4 pv = *(const ushort4*)(p + s * stride + (size_t)i * 4);
    v.x += bf2f(pv.x); v.y += bf2f(pv.y); v.z += bf2f(pv.z); v.w += bf2f(pv.w);
  }
  ((float4*)out)[i] = v;
}

// ---------------- RoPE + qkv split-K reduce (bf16 partials) + bias + split ----------------
__global__ __launch_bounds__(256)
void rope_split(const ushort* __restrict__ p, size_t stride, const float* __restrict__ qkvb,
                ushort* __restrict__ qb, ushort* __restrict__ kb, ushort* __restrict__ vb) {
  int tok = blockIdx.x;
  int tid = threadIdx.x;
  __shared__ float cs[32], sn[32];
  if (tid < 32) {
    float d = (float)tid;
    float freq = powf(150000.0f, d / 32.0f);
    float conc = 0.1f * logf(32.0f) + 1.0f;
    float lg = logf(150000.0f);
    float low = 32.0f * logf(4096.0f / (32.0f * 6.2831853f)) / lg;
    float high = 32.0f * logf(4096.0f / 6.2831853f) / lg;
    float ramp = (d - low) / (high - low);
    float cl = fminf(fmaxf(ramp, 0.0f), 1.0f);
    float mask = 1.0f - cl;
    float inv_freq = (1.0f - mask) / (32.0f * freq) + mask / freq;
    float fr = (float)tok * inv_freq;
    cs[tid] = cosf(fr) * conc;
    sn[tid] = sinf(fr) * conc;
  }
  __syncthreads();
  const ushort* r0 = p + (size_t)tok * QKV_DIM;
  const ushort* r1 = r0 + stride;
  auto ld = [&](int c) { return bf2f(r0[c]) + bf2f(r1[c]) + qkvb[c]; };
#pragma unroll
  for (int it = 0; it < 8; ++it) {
    int pp = tid + it * 256;
    int hd = pp >> 5, d = pp & 31;
    float x1 = ld(hd * 64 + d), x2 = ld(hd * 64 + d + 32);
    float c = cs[d], s = sn[d];
    size_t o = ((size_t)tok * NH + hd) * HD + d;
    qb[o] = f2bf(x1 * c - x2 * s);
    qb[o + 32] = f2bf(x2 * c + x1 * s);
  }
  {
    int pp = tid;
    int hd = pp >> 5, d = pp & 31;
    float x1 = ld(4096 + hd * 64 + d), x2 = ld(4096 + hd * 64 + d + 32);
    float c = cs[d], s = sn[d];
    size_t o = ((size_t)tok * NKV + hd) * HD + d;
    kb[o] = f2bf(x1 * c - x2 * s);
    kb[o + 32] = f2bf(x2 * c + x1 * s);
  }
#pragma unroll
  for (int it = 0; it < 2; ++it) {
    int pp = tid + it * 256;
    vb[(size_t)tok * (NKV * HD) + pp] = f2bf(ld(4608 + pp));
  }
}

// ---- attention (sliding window 128 + sink, 16 q/wave) + hidden out_w f32->bf16 cvt ----
__global__ __launch_bounds__(512)
void attn_cvt(const ushort* __restrict__ qb, const ushort* __restrict__ kb,
              const ushort* __restrict__ vb, const float* __restrict__ sinks,
              ushort* __restrict__ attn, int n, int nattn,
              const float* __restrict__ w, ushort* __restrict__ wout, int n4w) {
  __shared__ __align__(16) ushort Kl[160 * 64];
  __shared__ __align__(16) ushort Vt[64 * 168];
  __shared__ __align__(16) ushort Pl[8][16 * 40];
  int tid = threadIdx.x;
  if ((int)blockIdx.x >= nattn) {
    int i = ((int)blockIdx.x - nattn) * 512 + tid;
    int stride = (gridDim.x - nattn) * 512;
    for (; i < n4w; i += stride) {
      float4 v = ((const float4*)w)[i];
      ushort4 o = { f2bf(v.x), f2bf(v.y), f2bf(v.z), f2bf(v.w) };
      ((ushort4*)wout)[i] = o;
    }
    return;
  }
  int wave = tid >> 6, lane = tid & 63;
  int l15 = lane & 15, hi = lane >> 4;
  int qstart = ((int)blockIdx.x >> 3) * 16;
  int kv = (int)blockIdx.x & 7;
  int head = kv * 8 + wave;
  int key0 = qstart - 128;

  for (int i = 0; i < 3; ++i) {
    int rowb = i * 64 + wave * 8;
    if (rowb < 160) {
      int r = rowb + (lane >> 3);
      int gj = key0 + r; if (gj < 0) gj = 0;
      int chunk = (lane & 7) ^ (lane >> 3);
      gload_lds16(kb + ((size_t)gj * NKV + kv) * HD + chunk * 8, Kl + rowb * 64);
    }
  }
  for (int e = tid; e < 160 * 16; e += 512) {
    int j = e >> 4, d4 = (e & 15) << 2;
    int gj = key0 + j; if (gj < 0) gj = 0;
    ushort4 v = *(const ushort4*)(vb + ((size_t)gj * NKV + kv) * HD + d4);
    Vt[(d4 + 0) * 168 + j] = v.x;
    Vt[(d4 + 1) * 168 + j] = v.y;
    Vt[(d4 + 2) * 168 + j] = v.z;
    Vt[(d4 + 3) * 168 + j] = v.w;
  }
  bf16x8 qf[2];
#pragma unroll
  for (int ks = 0; ks < 2; ++ks) {
    int r = qstart + l15;
    int kk = ks * 32 + hi * 8;
    qf[ks] = *(const bf16x8*)(qb + ((size_t)r * NH + head) * HD + kk);
  }
  __syncthreads();

  f32x4 s[10] = {};
#pragma unroll
  for (int nt = 0; nt < 10; ++nt) {
#pragma unroll
    for (int ks = 0; ks < 2; ++ks) {
      int r = nt * 16 + l15;
      int off = (r * 128 + (ks * 32 + hi * 8) * 2) ^ ((r & 7) << 4);
      bf16x8 kf = *(const bf16x8*)((const char*)Kl + off);
      s[nt] = __builtin_amdgcn_mfma_f32_16x16x32_bf16(qf[ks], kf, s[nt], 0, 0, 0);
    }
  }

  float lrow[4];
  float snk = sinks[head];
#pragma unroll
  for (int r = 0; r < 4; ++r) {
    int i = qstart + hi * 4 + r;
    float mx = -1e30f;
#pragma unroll
    for (int nt = 0; nt < 10; ++nt) {
      int j = key0 + nt * 16 + l15;
      bool ok = (j >= 0) && (j <= i) && (j > i - WINDOW);
      float val = ok ? s[nt][r] * SM_SCALE : -1e30f;
      s[nt][r] = val;
      mx = fmaxf(mx, val);
    }
    mx = fmaxf(mx, __shfl_xor(mx, 1, 64));
    mx = fmaxf(mx, __shfl_xor(mx, 2, 64));
    mx = fmaxf(mx, __shfl_xor(mx, 4, 64));
    mx = fmaxf(mx, __shfl_xor(mx, 8, 64));
    mx = fmaxf(mx, snk);
    float sum = 0.f;
#pragma unroll
    for (int nt = 0; nt < 10; ++nt) {
      float pv = __expf(s[nt][r] - mx);
      s[nt][r] = pv;
      sum += pv;
    }
    sum += __shfl_xor(sum, 1, 64);
    sum += __shfl_xor(sum, 2, 64);
    sum += __shfl_xor(sum, 4, 64);
    sum += __shfl_xor(sum, 8, 64);
    sum += __expf(snk - mx);
    lrow[r] = sum;
  }

  f32x4 o[4] = {};
#pragma unroll
  for (int kc = 0; kc < 5; ++kc) {
#pragma unroll
    for (int t2 = 0; t2 < 2; ++t2) {
      int nt = kc * 2 + t2;
#pragma unroll
      for (int r = 0; r < 4; ++r)
        Pl[wave][(hi * 4 + r) * 40 + t2 * 16 + l15] = f2bf(s[nt][r]);
    }
    bf16x8 pa = *(const bf16x8*)(&Pl[wave][l15 * 40 + hi * 8]);
#pragma unroll
    for (int nt = 0; nt < 4; ++nt) {
      int d = nt * 16 + l15;
      int kk = kc * 32 + hi * 8;
      bf16x8 vf = *(const bf16x8*)(&Vt[d * 168 + kk]);
      o[nt] = __builtin_amdgcn_mfma_f32_16x16x32_bf16(pa, vf, o[nt], 0, 0, 0);
    }
  }

#pragma unroll
  for (int nt = 0; nt < 4; ++nt)
#pragma unroll
    for (int r = 0; r < 4; ++r) {
      int row = qstart + hi * 4 + r;
      int d = nt * 16 + l15;
      float val = o[nt][r] / lrow[r];
      attn[((size_t)row * NH + head) * HD + d] = f2bf(val);
    }
}

extern "C" void kernel_launch(void* const* d_in, const int* in_sizes, int n_in,
                              void* d_out, int out_size, void* d_ws, size_t ws_size,
                              hipStream_t stream) {
  const float* x      = (const float*)d_in[0];
  const float* nscale = (const float*)d_in[1];
  const float* qkv_w  = (const float*)d_in[2];
  const float* qkv_b  = (const float*)d_in[3];
  const float* out_w  = (const float*)d_in[4];
  const float* out_b  = (const float*)d_in[5];
  const float* sinks  = (const float*)d_in[6];
  float* out = (float*)d_out;
  int n = in_sizes[0] / HIDDEN;  // 1536

  char* ws = (char*)d_ws;
  size_t off = 0;
  auto alloc = [&](size_t bytes) {
    char* p = ws + off;
    off += (bytes + 255) & ~(size_t)255;
    return p;
  };
  ushort* t_bf    = (ushort*)alloc((size_t)n * HIDDEN * 2);
  ushort* qkvw_bf = (ushort*)alloc((size_t)QKV_DIM * HIDDEN * 2);
  ushort* outw_bf = (ushort*)alloc((size_t)HIDDEN * ATT_DIM * 2);
  ushort* q_bf    = (ushort*)alloc((size_t)n * NH * HD * 2);
  ushort* k_bf    = (ushort*)alloc((size_t)n * NKV * HD * 2);
  ushort* v_bf    = (ushort*)alloc((size_t)n * NKV * HD * 2);
  ushort* attn    = (ushort*)alloc((size_t)n * ATT_DIM * 2);
  size_t qkv_ps = (size_t)n * QKV_DIM;   // elements per qkv partial slice
  size_t out_ps = (size_t)n * HIDDEN;    // elements per out partial slice
  size_t pelems = 2 * qkv_ps > 3 * out_ps ? 2 * qkv_ps : 3 * out_ps;
  ushort* partials = (ushort*)alloc(pelems * 2);

  // fused rmsnorm (n blocks) + qkv_w cvt (1024 blocks)
  norm_cvt<<<n + 1024, 256, 0, stream>>>(x, nscale, t_bf, n,
                                         qkv_w, qkvw_bf, QKV_DIM * HIDDEN / 4);
  // QKV: M=1536 N=5120 K=2880, 256^2 tiles -> 6x20=120 wg, split-K x2 -> 240 wg
  gemm_8p<0><<<dim3((n / 256) * (QKV_DIM / 256), 2), 512, 0, stream>>>(
      t_bf, qkvw_bf, partials, n, QKV_DIM, HIDDEN, 2);
  rope_split<<<n, 256, 0, stream>>>(partials, qkv_ps, qkv_b, q_bf, k_bf, v_bf);
  // attention (768 blocks) + hidden out_w cvt (320 blocks)
  int nattn = (n / 16) * NKV;
  attn_cvt<<<nattn + 320, 512, 0, stream>>>(q_bf, k_bf, v_bf, sinks, attn, n, nattn,
                                            out_w, outw_bf, HIDDEN * ATT_DIM / 4);
  // out: M=1536 N=2880 K=4096 -> 6x12=72 wg (last N-panel masked), split-K x3 -> 216 wg
  gemm_8p<1><<<dim3((n / 256) * 12, 3), 512, 0, stream>>>(
      attn, outw_bf, partials, n, HIDDEN, ATT_DIM, 3);
  reduce_out<<<(n * HIDDEN / 4 + 255) / 256, 256, 0, stream>>>(
      x, out_b, partials, 3, out_ps, out, n * HIDDEN / 4, HIDDEN);
}

// Round 15
// 157.427 us; speedup vs baseline: 1.2898x; 1.0868x over previous
//
#include <hip/hip_runtime.h>

typedef __attribute__((ext_vector_type(8))) short bf16x8;
typedef __attribute__((ext_vector_type(4))) float f32x4;

#define HIDDEN 2880
#define QKV_DIM 5120
#define NH 64
#define NKV 8
#define HD 64
#define ATT_DIM 4096
#define WINDOW 128
#define SM_SCALE 0.125f

__device__ __forceinline__ ushort f2bf(float f) {
  union { float f; unsigned u; } a; a.f = f;
  unsigned r = a.u + 0x7fffu + ((a.u >> 16) & 1u);
  return (ushort)(r >> 16);
}
__device__ __forceinline__ float bf2f(ushort u) {
  union { unsigned u; float f; } a; a.u = ((unsigned)u) << 16;
  return a.f;
}

__device__ __forceinline__ void gload_lds16(const void* g, void* l) {
  __builtin_amdgcn_global_load_lds((const __attribute__((address_space(1))) void*)g,
                                   (__attribute__((address_space(3))) void*)l, 16, 0, 0);
}

// ------- fused: RMSNorm (blocks [0,n)) + qkv_w f32->bf16 cvt (blocks [n, n+1024)) -------
__global__ __launch_bounds__(256)
void norm_cvt(const float* __restrict__ x, const float* __restrict__ scale,
              ushort* __restrict__ t, int n,
              const float* __restrict__ w, ushort* __restrict__ wout, int n4w) {
  int tid = threadIdx.x;
  if ((int)blockIdx.x >= n) {
    int i = ((int)blockIdx.x - n) * 256 + tid;
    int stride = (gridDim.x - n) * 256;
    for (; i < n4w; i += stride) {
      float4 v = ((const float4*)w)[i];
      ushort4 o = { f2bf(v.x), f2bf(v.y), f2bf(v.z), f2bf(v.w) };
      ((ushort4*)wout)[i] = o;
    }
    return;
  }
  int row = blockIdx.x;
  const float4* xr = (const float4*)(x + (size_t)row * HIDDEN);
  float4 a0 = xr[tid];
  float4 a1 = xr[tid + 256];
  bool has2 = tid < 208;
  float4 a2 = has2 ? xr[tid + 512] : float4{0.f, 0.f, 0.f, 0.f};
  float ss = a0.x*a0.x + a0.y*a0.y + a0.z*a0.z + a0.w*a0.w
           + a1.x*a1.x + a1.y*a1.y + a1.z*a1.z + a1.w*a1.w
           + a2.x*a2.x + a2.y*a2.y + a2.z*a2.z + a2.w*a2.w;
  for (int m = 1; m < 64; m <<= 1) ss += __shfl_xor(ss, m, 64);
  __shared__ float red[4];
  if ((tid & 63) == 0) red[tid >> 6] = ss;
  __syncthreads();
  ss = red[0] + red[1] + red[2] + red[3];
  float r = rsqrtf(ss / (float)HIDDEN + 1e-5f);
  ushort4* tr = (ushort4*)(t + (size_t)row * HIDDEN);
  const float4* sc4 = (const float4*)scale;
  {
    float4 s = sc4[tid];
    ushort4 o = { f2bf(a0.x*r*s.x), f2bf(a0.y*r*s.y), f2bf(a0.z*r*s.z), f2bf(a0.w*r*s.w) };
    tr[tid] = o;
  }
  {
    float4 s = sc4[tid + 256];
    ushort4 o = { f2bf(a1.x*r*s.x), f2bf(a1.y*r*s.y), f2bf(a1.z*r*s.z), f2bf(a1.w*r*s.w) };
    tr[tid + 256] = o;
  }
  if (has2) {
    float4 s = sc4[tid + 512];
    ushort4 o = { f2bf(a2.x*r*s.x), f2bf(a2.y*r*s.y), f2bf(a2.z*r*s.z), f2bf(a2.w*r*s.w) };
    tr[tid + 512] = o;
  }
}

// -------- 256x256 8-phase pipelined bf16 GEMM (split-K): P[sk] = A * B^T K-slice --------
// EXACT R7/R11 schedule (best measured). bf16 partials.
template <int MASK_N>
__global__ __launch_bounds__(512)
void gemm_8p(const ushort* __restrict__ A, const ushort* __restrict__ B,
             ushort* __restrict__ P, int M, int N, int K, int NSK) {
  __shared__ __align__(16) ushort Al[2][256 * 64];
  __shared__ __align__(16) ushort Bl[2][256 * 64];
  const int tid = threadIdx.x;
  const int wave = tid >> 6, lane = tid & 63;
  const int l15 = lane & 15, hi = lane >> 4;

  int nwg = gridDim.x, orig = blockIdx.x;
  int q8 = nwg >> 3, r8 = nwg & 7, xcd = orig & 7, seq = orig >> 3;
  int swz = (xcd < r8 ? xcd * (q8 + 1) : r8 * (q8 + 1) + (xcd - r8) * q8) + seq;
  int nm = M >> 8;
  int bm = swz % nm, bn = swz / nm;
  const int row0 = bm * 256, col0 = bn * 256;
  const int sk = blockIdx.y;
  const int NTtot = K >> 6;
  const int tt0 = sk * NTtot / NSK, tt1 = (sk + 1) * NTtot / NSK;
  ushort* Pp = P + (size_t)sk * M * N;

  const int wrow = (wave >> 2) * 128;
  const int wcol = (wave & 3) * 64;
  const int srow = lane >> 3;
  const int schunk = (lane & 7) ^ srow;

  f32x4 acc[8][4] = {};

  auto stageA = [&](int t, int r) {
    int row = row0 + r * 64 + wave * 8 + srow;
    gload_lds16(A + (size_t)row * K + (t << 6) + schunk * 8,
                &Al[t & 1][(r * 64 + wave * 8) * 64]);
  };
  auto stageB = [&](int t, int r) {
    int brow = col0 + r * 64 + wave * 8 + srow;
    if (MASK_N) { if (brow > N - 1) brow = N - 1; }
    gload_lds16(B + (size_t)brow * K + (t << 6) + schunk * 8,
                &Bl[t & 1][(r * 64 + wave * 8) * 64]);
  };
  auto stageAll = [&](int t) {
#pragma unroll
    for (int r = 0; r < 4; ++r) { stageA(t, r); stageB(t, r); }
  };
  auto LDA = [&](bf16x8 (&dst)[4][2], int mh, const char* base) {
#pragma unroll
    for (int mt = 0; mt < 4; ++mt)
#pragma unroll
      for (int ks = 0; ks < 2; ++ks) {
        int rr = wrow + mh * 64 + mt * 16 + l15;
        int off = (rr * 128 + ks * 64 + hi * 16) ^ ((rr & 7) << 4);
        dst[mt][ks] = *(const bf16x8*)(base + off);
      }
  };
  auto LDB = [&](bf16x8 (&dst)[2][2], int nh, const char* base) {
#pragma unroll
    for (int nt = 0; nt < 2; ++nt)
#pragma unroll
      for (int ks = 0; ks < 2; ++ks) {
        int rr = wcol + nh * 32 + nt * 16 + l15;
        int off = (rr * 128 + ks * 64 + hi * 16) ^ ((rr & 7) << 4);
        dst[nt][ks] = *(const bf16x8*)(base + off);
      }
  };
  auto MMA = [&](bf16x8 (&a)[4][2], bf16x8 (&b)[2][2], int mh, int nh) {
    __builtin_amdgcn_s_setprio(1);
#pragma unroll
    for (int ks = 0; ks < 2; ++ks)
#pragma unroll
      for (int nt = 0; nt < 2; ++nt)
#pragma unroll
        for (int mt = 0; mt < 4; ++mt)
          acc[mh * 4 + mt][nh * 2 + nt] = __builtin_amdgcn_mfma_f32_16x16x32_bf16(
              a[mt][ks], b[nt][ks], acc[mh * 4 + mt][nh * 2 + nt], 0, 0, 0);
    __builtin_amdgcn_s_setprio(0);
  };

  stageAll(tt0);
  bool two = (tt1 - tt0 > 1);
  if (two) {
    stageAll(tt0 + 1);
    asm volatile("s_waitcnt vmcnt(8)" ::: "memory");
  } else {
    asm volatile("s_waitcnt vmcnt(0)" ::: "memory");
  }
  __builtin_amdgcn_s_barrier();

  for (int t = tt0; t < tt1; ++t) {
    const char* Ab = (const char*)&Al[t & 1][0];
    const char* Bb = (const char*)&Bl[t & 1][0];
    bool pre = (t + 2 < tt1);
    bf16x8 afr[4][2], bf0[2][2], bf1[2][2];
    // P1
    LDA(afr, 0, Ab);
    LDB(bf0, 0, Bb);
    __builtin_amdgcn_s_barrier();
    MMA(afr, bf0, 0, 0);
    __builtin_amdgcn_s_barrier();
    // P2
    LDB(bf1, 1, Bb);
    if (pre) { stageA(t + 2, 0); stageA(t + 2, 2); }
    __builtin_amdgcn_s_barrier();
    MMA(afr, bf1, 0, 1);
    __builtin_amdgcn_s_barrier();
    // P3
    LDA(afr, 1, Ab);
    if (pre) { stageB(t + 2, 0); stageB(t + 2, 1); stageB(t + 2, 2); stageB(t + 2, 3); }
    __builtin_amdgcn_s_barrier();
    MMA(afr, bf1, 1, 1);
    __builtin_amdgcn_s_barrier();
    // P4
    if (pre) { stageA(t + 2, 1); stageA(t + 2, 3); }
    __builtin_amdgcn_s_barrier();
    MMA(afr, bf0, 1, 0);
    if (pre) asm volatile("s_waitcnt vmcnt(8)" ::: "memory");
    else     asm volatile("s_waitcnt vmcnt(0)" ::: "memory");
    __builtin_amdgcn_s_barrier();
  }

  // epilogue: C/D layout col=lane&15, row=(lane>>4)*4+r (m89-verified); bf16 partials
#pragma unroll
  for (int mtg = 0; mtg < 8; ++mtg) {
#pragma unroll
    for (int nt = 0; nt < 4; ++nt) {
#pragma unroll
      for (int rr = 0; rr < 4; ++rr) {
        int row = row0 + wrow + mtg * 16 + (hi << 2) + rr;
        int col = col0 + wcol + nt * 16 + l15;
        if (!MASK_N || col < N) Pp[(size_t)row * N + col] = f2bf(acc[mtg][nt][rr]);
      }
    }
  }
}

// ---------------- out reduce: out = x + out_b + sum_sk bf16 partials ----------------
__global__ __launch_bounds__(256)
void reduce_out(const float* __restrict__ x, const float* __restrict__ b,
                const ushort* __restrict__ p, int nsk, size_t stride,
                float* __restrict__ out, int n4, int N) {
  int i = blockIdx.x * blockDim.x + threadIdx.x;
  if (i >= n4) return;
  float4 v = ((const float4*)x)[i];
  int col = (i * 4) % N;
  float4 bb = *(const float4*)(b + col);
  v.x += bb.x; v.y += bb.y; v.z += bb.z; v.w += bb.w;
  for (int s = 0; s < nsk; ++s) {
    ushort4 pv = *(const ushort4*)(p + s * stride + (size_t)i * 4);
    v.x += bf2f(pv.x); v.y += bf2f(pv.y); v.z += bf2f(pv.z); v.w += bf2f(pv.w);
  }
  ((float4*)out)[i] = v;
}

// ---- attention (sliding window 128 + sink, 16 q/wave) reading QKV PARTIALS directly ----
// RoPE fused into staging: K reg-staged (rope -> ds_write with SAME XOR as reads),
// V = 2-slice sum + bias (no rope), Q fragments roped in-register. rope_split deleted.
// Blocks [nattn, grid) convert out_w f32->bf16 concurrently (unchanged).
__global__ __launch_bounds__(512)
void attn_cvt(const ushort* __restrict__ p, size_t stride, const float* __restrict__ qkvb,
              const float* __restrict__ sinks, ushort* __restrict__ attn, int n, int nattn,
              const float* __restrict__ w, ushort* __restrict__ wout, int n4w) {
  __shared__ __align__(16) ushort Kl[160 * 64];
  __shared__ __align__(16) ushort Vt[64 * 168];
  __shared__ __align__(16) ushort Pl[8][16 * 40];
  __shared__ float invf[32];
  __shared__ float conc_s;
  int tid = threadIdx.x;
  if ((int)blockIdx.x >= nattn) {
    int i = ((int)blockIdx.x - nattn) * 512 + tid;
    int gstride = (gridDim.x - nattn) * 512;
    for (; i < n4w; i += gstride) {
      float4 v = ((const float4*)w)[i];
      ushort4 o = { f2bf(v.x), f2bf(v.y), f2bf(v.z), f2bf(v.w) };
      ((ushort4*)wout)[i] = o;
    }
    return;
  }
  int wave = tid >> 6, lane = tid & 63;
  int l15 = lane & 15, hi = lane >> 4;
  int qstart = ((int)blockIdx.x >> 3) * 16;
  int kv = (int)blockIdx.x & 7;
  int head = kv * 8 + wave;
  int key0 = qstart - 128;

  // inv_freq table (32 entries, token-independent) + concentration
  if (tid < 32) {
    float d = (float)tid;
    float freq = powf(150000.0f, d / 32.0f);
    float lg = logf(150000.0f);
    float low = 32.0f * logf(4096.0f / (32.0f * 6.2831853f)) / lg;
    float high = 32.0f * logf(4096.0f / 6.2831853f) / lg;
    float ramp = (d - low) / (high - low);
    float cl = fminf(fmaxf(ramp, 0.0f), 1.0f);
    float mask = 1.0f - cl;
    invf[tid] = (1.0f - mask) / (32.0f * freq) + mask / freq;
    if (tid == 0) conc_s = 0.1f * logf(32.0f) + 1.0f;
  }
  __syncthreads();
  float conc = conc_s;

  // helper: summed+biased f32 from 2 bf16 partial slices
  const ushort* r0b = p;
  const ushort* r1b = p + stride;

  // ---- K staging: 160 rows x 8 chunks = 1280 tasks, reg-staged rope -> swizzled ds_write
  for (int i = 0; i < 3; ++i) {
    int task = tid + i * 512;
    if (task < 1280) {
      int rb = task >> 3, ch = task & 7;
      int gj = key0 + rb; if (gj < 0) gj = 0;
      size_t base = (size_t)gj * QKV_DIM + 4096 + kv * 64;
      int d0 = ch * 8, d0p = d0 ^ 32;
      bf16x8 a0 = *(const bf16x8*)(r0b + base + d0);
      bf16x8 a1 = *(const bf16x8*)(r1b + base + d0);
      bf16x8 b0 = *(const bf16x8*)(r0b + base + d0p);
      bf16x8 b1 = *(const bf16x8*)(r1b + base + d0p);
      bf16x8 o;
#pragma unroll
      for (int j = 0; j < 8; ++j) {
        float xv = bf2f((ushort)a0[j]) + bf2f((ushort)a1[j]) + qkvb[4096 + kv * 64 + d0 + j];
        float yv = bf2f((ushort)b0[j]) + bf2f((ushort)b1[j]) + qkvb[4096 + kv * 64 + d0p + j];
        int d31 = (d0 + j) & 31;
        float fr = (float)gj * invf[d31];
        float c, s;
        __sincosf(fr, &s, &c);
        c *= conc; s *= conc;
        float v = (d0 < 32) ? (xv * c - yv * s) : (xv * c + yv * s);
        o[j] = (short)f2bf(v);
      }
      int off = (rb * 128 + ch * 16) ^ ((rb & 7) << 4);
      *(bf16x8*)((char*)Kl + off) = o;
    }
  }
  // ---- V staging: transpose, 2-slice sum + bias (no rope)
  for (int e = tid; e < 160 * 16; e += 512) {
    int j = e >> 4, d4 = (e & 15) << 2;
    int gj = key0 + j; if (gj < 0) gj = 0;
    size_t base = (size_t)gj * QKV_DIM + 4608 + kv * 64 + d4;
    ushort4 v0 = *(const ushort4*)(r0b + base);
    ushort4 v1 = *(const ushort4*)(r1b + base);
    const float* bb = qkvb + 4608 + kv * 64 + d4;
    Vt[(d4 + 0) * 168 + j] = f2bf(bf2f(v0.x) + bf2f(v1.x) + bb[0]);
    Vt[(d4 + 1) * 168 + j] = f2bf(bf2f(v0.y) + bf2f(v1.y) + bb[1]);
    Vt[(d4 + 2) * 168 + j] = f2bf(bf2f(v0.z) + bf2f(v1.z) + bb[2]);
    Vt[(d4 + 3) * 168 + j] = f2bf(bf2f(v0.w) + bf2f(v1.w) + bb[3]);
  }
  // ---- Q fragments: rope in-register
  bf16x8 qf[2];
  {
    int tok = qstart + l15;
    size_t base = (size_t)tok * QKV_DIM + head * 64;
    float cs8[8], sn8[8];
#pragma unroll
    for (int j = 0; j < 8; ++j) {
      int d31 = hi * 8 + j;
      float fr = (float)tok * invf[d31];
      float c, s;
      __sincosf(fr, &s, &c);
      cs8[j] = c * conc; sn8[j] = s * conc;
    }
#pragma unroll
    for (int ks = 0; ks < 2; ++ks) {
      int d0 = ks * 32 + hi * 8, d0p = d0 ^ 32;
      bf16x8 a0 = *(const bf16x8*)(r0b + base + d0);
      bf16x8 a1 = *(const bf16x8*)(r1b + base + d0);
      bf16x8 b0 = *(const bf16x8*)(r0b + base + d0p);
      bf16x8 b1 = *(const bf16x8*)(r1b + base + d0p);
#pragma unroll
      for (int j = 0; j < 8; ++j) {
        float xv = bf2f((ushort)a0[j]) + bf2f((ushort)a1[j]) + qkvb[head * 64 + d0 + j];
        float yv = bf2f((ushort)b0[j]) + bf2f((ushort)b1[j]) + qkvb[head * 64 + d0p + j];
        float v = (ks == 0) ? (xv * cs8[j] - yv * sn8[j]) : (xv * cs8[j] + yv * sn8[j]);
        qf[ks][j] = (short)f2bf(v);
      }
    }
  }
  __syncthreads();

  f32x4 s[10] = {};
#pragma unroll
  for (int nt = 0; nt < 10; ++nt) {
#pragma unroll
    for (int ks = 0; ks < 2; ++ks) {
      int r = nt * 16 + l15;
      int off = (r * 128 + (ks * 32 + hi * 8) * 2) ^ ((r & 7) << 4);
      bf16x8 kf = *(const bf16x8*)((const char*)Kl + off);
      s[nt] = __builtin_amdgcn_mfma_f32_16x16x32_bf16(qf[ks], kf, s[nt], 0, 0, 0);
    }
  }

  float lrow[4];
  float snk = sinks[head];
#pragma unroll
  for (int r = 0; r < 4; ++r) {
    int i = qstart + hi * 4 + r;
    float mx = -1e30f;
#pragma unroll
    for (int nt = 0; nt < 10; ++nt) {
      int j = key0 + nt * 16 + l15;
      bool ok = (j >= 0) && (j <= i) && (j > i - WINDOW);
      float val = ok ? s[nt][r] * SM_SCALE : -1e30f;
      s[nt][r] = val;
      mx = fmaxf(mx, val);
    }
    mx = fmaxf(mx, __shfl_xor(mx, 1, 64));
    mx = fmaxf(mx, __shfl_xor(mx, 2, 64));
    mx = fmaxf(mx, __shfl_xor(mx, 4, 64));
    mx = fmaxf(mx, __shfl_xor(mx, 8, 64));
    mx = fmaxf(mx, snk);
    float sum = 0.f;
#pragma unroll
    for (int nt = 0; nt < 10; ++nt) {
      float pv = __expf(s[nt][r] - mx);
      s[nt][r] = pv;
      sum += pv;
    }
    sum += __shfl_xor(sum, 1, 64);
    sum += __shfl_xor(sum, 2, 64);
    sum += __shfl_xor(sum, 4, 64);
    sum += __shfl_xor(sum, 8, 64);
    sum += __expf(snk - mx);
    lrow[r] = sum;
  }

  f32x4 o[4] = {};
#pragma unroll
  for (int kc = 0; kc < 5; ++kc) {
#pragma unroll
    for (int t2 = 0; t2 < 2; ++t2) {
      int nt = kc * 2 + t2;
#pragma unroll
      for (int r = 0; r < 4; ++r)
        Pl[wave][(hi * 4 + r) * 40 + t2 * 16 + l15] = f2bf(s[nt][r]);
    }
    bf16x8 pa = *(const bf16x8*)(&Pl[wave][l15 * 40 + hi * 8]);
#pragma unroll
    for (int nt = 0; nt < 4; ++nt) {
      int d = nt * 16 + l15;
      int kk = kc * 32 + hi * 8;
      bf16x8 vf = *(const bf16x8*)(&Vt[d * 168 + kk]);
      o[nt] = __builtin_amdgcn_mfma_f32_16x16x32_bf16(pa, vf, o[nt], 0, 0, 0);
    }
  }

#pragma unroll
  for (int nt = 0; nt < 4; ++nt)
#pragma unroll
    for (int r = 0; r < 4; ++r) {
      int row = qstart + hi * 4 + r;
      int d = nt * 16 + l15;
      float val = o[nt][r] / lrow[r];
      attn[((size_t)row * NH + head) * HD + d] = f2bf(val);
    }
}

extern "C" void kernel_launch(void* const* d_in, const int* in_sizes, int n_in,
                              void* d_out, int out_size, void* d_ws, size_t ws_size,
                              hipStream_t stream) {
  const float* x      = (const float*)d_in[0];
  const float* nscale = (const float*)d_in[1];
  const float* qkv_w  = (const float*)d_in[2];
  const float* qkv_b  = (const float*)d_in[3];
  const float* out_w  = (const float*)d_in[4];
  const float* out_b  = (const float*)d_in[5];
  const float* sinks  = (const float*)d_in[6];
  float* out = (float*)d_out;
  int n = in_sizes[0] / HIDDEN;  // 1536

  char* ws = (char*)d_ws;
  size_t off = 0;
  auto alloc = [&](size_t bytes) {
    char* p = ws + off;
    off += (bytes + 255) & ~(size_t)255;
    return p;
  };
  ushort* t_bf    = (ushort*)alloc((size_t)n * HIDDEN * 2);
  ushort* qkvw_bf = (ushort*)alloc((size_t)QKV_DIM * HIDDEN * 2);
  ushort* outw_bf = (ushort*)alloc((size_t)HIDDEN * ATT_DIM * 2);
  ushort* attn    = (ushort*)alloc((size_t)n * ATT_DIM * 2);
  size_t qkv_ps = (size_t)n * QKV_DIM;   // elements per qkv partial slice
  size_t out_ps = (size_t)n * HIDDEN;    // elements per out partial slice
  size_t pelems = 2 * qkv_ps > 3 * out_ps ? 2 * qkv_ps : 3 * out_ps;
  ushort* partials = (ushort*)alloc(pelems * 2);

  // fused rmsnorm (n blocks) + qkv_w cvt (1024 blocks)
  norm_cvt<<<n + 1024, 256, 0, stream>>>(x, nscale, t_bf, n,
                                         qkv_w, qkvw_bf, QKV_DIM * HIDDEN / 4);
  // QKV: M=1536 N=5120 K=2880, 256^2 tiles -> 6x20=120 wg, split-K x2 -> 240 wg
  gemm_8p<0><<<dim3((n / 256) * (QKV_DIM / 256), 2), 512, 0, stream>>>(
      t_bf, qkvw_bf, partials, n, QKV_DIM, HIDDEN, 2);
  // attention w/ fused rope+reduce+bias (768 blocks) + hidden out_w cvt (320 blocks)
  int nattn = (n / 16) * NKV;
  attn_cvt<<<nattn + 320, 512, 0, stream>>>(partials, qkv_ps, qkv_b, sinks, attn, n, nattn,
                                            out_w, outw_bf, HIDDEN * ATT_DIM / 4);
  // out: M=1536 N=2880 K=4096 -> 6x12=72 wg (last N-panel masked), split-K x3 -> 216 wg
  gemm_8p<1><<<dim3((n / 256) * 12, 3), 512, 0, stream>>>(
      attn, outw_bf, partials, n, HIDDEN, ATT_DIM, 3);
  reduce_out<<<(n * HIDDEN / 4 + 255) / 256, 256, 0, stream>>>(
      x, out_b, partials, 3, out_ps, out, n * HIDDEN / 4, HIDDEN);
}